// Round 1
// 460.783 us; speedup vs baseline: 1.0395x; 1.0395x over previous
//
#include <hip/hip_runtime.h>

// Problem constants
#define BB   128   // batch
#define CI   64    // in channels
#define HH   32
#define WW   32
#define CO   128   // out channels
#define IF   576   // CI*9
#define OW   32    // conv out w
#define XH   34    // haloed H
#define XW   34    // haloed W
// x' layout: [XH][XW][CI][BB] bf16(ushort);  (h',w',c,b) with h'=h+1 halo
#define XP_CB    (CI*BB)              // 8192
#define XP_ELEMS ((size_t)XH*XW*CI*BB)  // 9,469,952
#define BK   32    // K-chunk = one MFMA K-step
#define NIT  72    // 4 locations * 18 chunks
#define LDK  40    // padded LDS row (20 dwords; 16B-aligned rows, 2-way-max b128)
#define COB  64    // per-block c_out tile (CO split across 2 blocks)

using short8 = __attribute__((ext_vector_type(8))) short;
using bf16x4 = __attribute__((ext_vector_type(4))) short;
using f32x4  = __attribute__((ext_vector_type(4))) float;

__device__ __forceinline__ unsigned short f2bf(float f) {
  union { float f; unsigned int u; } v; v.f = f;
  unsigned int u = v.u;
  u = (u + 0x7FFFu + ((u >> 16) & 1u)) >> 16;   // RNE; inputs are finite
  return (unsigned short)u;
}

// ---- pass 1: x (B,C,H,W) fp32 -> x' (H+2,W+2,C,B) bf16 with zero halo ----
__global__ __launch_bounds__(256) void transpose_x(
    const float* __restrict__ x, unsigned short* __restrict__ xp) {
  const int c = blockIdx.x >> 5;   // 0..63
  const int h = blockIdx.x & 31;   // 0..31
  __shared__ __align__(16) unsigned short tile[32][136]; // 272B row: 16B-mult
  const int t = threadIdx.x;
  const int w = t & 31, b0 = t >> 5;         // b0 0..7
#pragma unroll
  for (int p = 0; p < 16; ++p) {
    int b = b0 + p * 8;
    float v = x[(((size_t)b * CI + c) * HH + h) * WW + w];
    tile[w][b] = f2bf(v);
  }
  __syncthreads();
  const int w2 = t >> 3;                 // 0..31
  const int bb = (t & 7) * 16;           // 0..112
  const unsigned short* src = &tile[w2][bb];
  unsigned short* dst = xp + ((size_t)(h + 1) * XW + (w2 + 1)) * XP_CB + c * BB + bb;
  *(uint4*)(dst)     = *(const uint4*)(src);
  *(uint4*)(dst + 8) = *(const uint4*)(src + 8);
}

// ---- pass 2: per-pooled-cell GEMMs + bias + relu + maxpool ----
// 512 blocks (pooled cell x CO-half) x 512 threads (8 waves) -> 2 blocks/CU,
// 16 waves/CU (4/SIMD) for latency hiding; weight still read exactly once.
__global__ __launch_bounds__(512, 4) void local_gemm_pool(
    const float* __restrict__ Wt, const float* __restrict__ bias,
    const unsigned short* __restrict__ xp, float* __restrict__ out) {
  __shared__ __align__(16) unsigned short Asl[2][BB][LDK];   // 20.0 KB
  __shared__ __align__(16) unsigned short Bsl[2][COB][LDK];  // 10.0 KB
  __shared__ int offs[IF];                                   // 2.25 KB

  const int tid  = threadIdx.x;
  const int lane = tid & 63;
  const int wave = tid >> 6;   // 0..7

  // im2col offset LUT (in x' elements): kk -> (di*34+dj)*8192 + c*128
  for (int kk = tid; kk < IF; kk += 512) {
    int c = kk / 9, r = kk % 9, di = r / 3, dj = r % 3;
    offs[kk] = ((di * XW + dj) * CI + c) * BB;
  }

  // XCD swizzle: blockIdx%8 = XCD; all pw and both coh of a ph-row on one XCD
  // so output 64B lines merge in that XCD's L2 and the coh pair shares xp.
  const int bidx = blockIdx.x;
  const int x8 = bidx & 7, j = bidx >> 3;       // j 0..63
  const int coh = j & 1;
  const int pw  = (j >> 1) & 15;
  const int ph  = 2 * x8 + (j >> 5);
  const int co0 = coh * COB;

  // staging ids
  const int sa = tid & 127;      // A: batch lane (256B coalesced)
  const int ka = tid >> 7;       // 0..3 : 8-k group (wave-pair uniform)
  const int sb = tid & 63;       // B: c_out lane (256B coalesced)
  const int kb = tid >> 6;       // 0..7 : 4-k group (wave uniform)

  // compute ids (mfma 16x16x32 layouts, HW-verified)
  const int r16 = lane & 15;
  const int q8  = (lane >> 4) * 8;
  const int m0  = (wave >> 2) * 64;   // batch tile: 2 x 64
  const int n0  = (wave & 3) * 16;    // c_out tile: 4 x 16

  f32x4 acc[4] = {};
  f32x4 rmx[4] = {};   // relu => max >= 0, so 0-init is exact

  float          breg0[4], breg1[4];
  unsigned short areg0[8], areg1[8];

  __syncthreads();  // offs ready

  auto issue = [&](int it, float* br, unsigned short* ar) {
    const int loc = it / 18, kc = it % 18, k0 = kc * BK;
    const int oh = 2 * ph + (loc >> 1), ow = 2 * pw + (loc & 1);
    const int l  = oh * OW + ow;
    const float* wp = Wt + ((size_t)l * IF + (k0 + kb * 4)) * CO + co0 + sb;
#pragma unroll
    for (int i = 0; i < 4; ++i) br[i] = wp[(size_t)i * CO];
    const int base = (oh * XW + ow) * XP_CB + sa;
#pragma unroll
    for (int i = 0; i < 8; ++i) ar[i] = xp[base + offs[k0 + ka * 8 + i]];
  };

  auto writeLds = [&](int it, const float* br, const unsigned short* ar) {
    const int bufI = it & 1;
    bf16x4 vb;
#pragma unroll
    for (int i = 0; i < 4; ++i) vb[i] = (short)f2bf(br[i]);
    *(bf16x4*)&Bsl[bufI][sb][kb * 4] = vb;   // b64, 8B-aligned
    short8 va;
#pragma unroll
    for (int i = 0; i < 8; ++i) va[i] = (short)ar[i];
    *(short8*)&Asl[bufI][sa][ka * 8] = va;   // b128, 16B-aligned
  };

  auto computeChunk = [&](int it) {
    const int bufI = it & 1;
    short8 af[4], bf;
#pragma unroll
    for (int tm = 0; tm < 4; ++tm)
      af[tm] = *(const short8*)&Asl[bufI][m0 + tm * 16 + r16][q8];
    bf = *(const short8*)&Bsl[bufI][n0 + r16][q8];
#pragma unroll
    for (int tm = 0; tm < 4; ++tm)
      acc[tm] = __builtin_amdgcn_mfma_f32_16x16x32_bf16(af[tm], bf, acc[tm], 0, 0, 0);
  };

  auto finishLoc = [&](int loc) {
    const int oh = 2 * ph + (loc >> 1), ow = 2 * pw + (loc & 1);
    const int l  = oh * OW + ow;
    const float bv = bias[l * CO + co0 + n0 + r16];
#pragma unroll
    for (int tm = 0; tm < 4; ++tm)
#pragma unroll
      for (int e = 0; e < 4; ++e) {
        float v = acc[tm][e] + bv;
        v = v > 0.f ? v : 0.f;
        rmx[tm][e] = fmaxf(rmx[tm][e], v);
        acc[tm][e] = 0.f;
      }
  };

  // 2-buffer reg-staged pipeline prologue
  issue(0, breg0, areg0);
  issue(1, breg1, areg1);
  writeLds(0, breg0, areg0);   // one prologue vmcnt stall
  __syncthreads();             // buf0 ready

  for (int it2 = 0; it2 < NIT; it2 += 2) {
    // even slot: compute buf0, stage buf1
    if (it2 + 2 < NIT) issue(it2 + 2, breg0, areg0);
    computeChunk(it2);
    writeLds(it2 + 1, breg1, areg1);          // it2+1 <= NIT-1 always
    __syncthreads();
    // odd slot: compute buf1, stage buf0
    const int ito = it2 + 1;
    if (ito + 2 < NIT) issue(ito + 2, breg1, areg1);
    computeChunk(ito);
    if (ito + 1 < NIT) writeLds(ito + 1, breg0, areg0);
    if (ito % 18 == 17) finishLoc(ito / 18);  // loc boundaries are odd its
    __syncthreads();
  }

  // store pooled tile; C/D: col=lane&15, row=(lane>>4)*4+e
  float* op = out + (ph * 16 + pw);
  const int col = co0 + n0 + r16;             // c_out
#pragma unroll
  for (int tm = 0; tm < 4; ++tm)
#pragma unroll
    for (int e = 0; e < 4; ++e) {
      const int row = m0 + tm * 16 + (lane >> 4) * 4 + e;  // batch
      op[((size_t)row * CO + col) * 256] = rmx[tm][e];
    }
}

extern "C" void kernel_launch(void* const* d_in, const int* in_sizes, int n_in,
                              void* d_out, int out_size, void* d_ws, size_t ws_size,
                              hipStream_t stream) {
  (void)in_sizes; (void)n_in; (void)out_size; (void)ws_size;
  const float* x  = (const float*)d_in[0];
  const float* w  = (const float*)d_in[1];
  const float* bs = (const float*)d_in[2];
  float* out = (float*)d_out;
  unsigned short* xp = (unsigned short*)d_ws;   // needs 18.94 MB scratch

  hipMemsetAsync(xp, 0, XP_ELEMS * sizeof(unsigned short), stream); // zero halo
  transpose_x<<<dim3(CI * HH), dim3(256), 0, stream>>>(x, xp);
  local_gemm_pool<<<dim3(512), dim3(512), 0, stream>>>(w, bs, xp, out);
}

// Round 2
// 460.277 us; speedup vs baseline: 1.0406x; 1.0011x over previous
//
#include <hip/hip_runtime.h>

// Problem constants
#define BB   128   // batch
#define CI   64    // in channels
#define HH   32
#define WW   32
#define CO   128   // out channels
#define IF   576   // CI*9
#define OW   32    // conv out w
#define XH   34    // haloed H
#define XW   34    // haloed W
// x' layout: [XH][XW][CI][BB] bf16(ushort);  (h',w',c,b) with h'=h+1 halo
#define XP_CB    (CI*BB)              // 8192
#define XP_ELEMS ((size_t)XH*XW*CI*BB)  // 9,469,952
#define BK   32    // K-chunk = one MFMA K-step
#define NIT  72    // 4 locations * 18 chunks
#define LDK  40    // padded LDS row (20 dwords; 16B-aligned rows, 2-way-max b128)
#define COB  64    // per-block c_out tile (CO split across 2 blocks)

using short8 = __attribute__((ext_vector_type(8))) short;
using f32x4  = __attribute__((ext_vector_type(4))) float;

__device__ __forceinline__ unsigned short f2bf(float f) {
  union { float f; unsigned int u; } v; v.f = f;
  unsigned int u = v.u;
  u = (u + 0x7FFFu + ((u >> 16) & 1u)) >> 16;   // RNE; inputs are finite
  return (unsigned short)u;
}

// HW packed fp32->bf16 (RNE), no builtin on gfx950 -> inline asm
__device__ __forceinline__ unsigned int cvt_pk_bf16(float lo, float hi) {
  unsigned int r;
  asm("v_cvt_pk_bf16_f32 %0, %1, %2" : "=v"(r) : "v"(lo), "v"(hi));
  return r;
}

// ---- pass 1: x (B,C,H,W) fp32 -> x' (H+2,W+2,C,B) bf16; halo zeroed by
// the first 132 blocks (replaces the 19 MB memset with 2.2 MB of writes) ----
__global__ __launch_bounds__(256) void transpose_x(
    const float* __restrict__ x, unsigned short* __restrict__ xp) {
  const int c = blockIdx.x >> 5;   // 0..63
  const int h = blockIdx.x & 31;   // 0..31
  __shared__ __align__(16) unsigned short tile[32][136]; // 272B row: 16B-mult
  const int t = threadIdx.x;
  const int w = t & 31, b0 = t >> 5;         // b0 0..7
#pragma unroll
  for (int p = 0; p < 16; ++p) {
    int b = b0 + p * 8;
    float v = x[(((size_t)b * CI + c) * HH + h) * WW + w];
    tile[w][b] = f2bf(v);
  }
  __syncthreads();
  const int w2 = t >> 3;                 // 0..31
  const int bb = (t & 7) * 16;           // 0..112
  const unsigned short* src = &tile[w2][bb];
  unsigned short* dst = xp + ((size_t)(h + 1) * XW + (w2 + 1)) * XP_CB + c * BB + bb;
  *(uint4*)(dst)     = *(const uint4*)(src);
  *(uint4*)(dst + 8) = *(const uint4*)(src + 8);

  // halo zero: 132 spans of 8192 ushorts (16 KB each)
  if (blockIdx.x < 132) {
    int s = blockIdx.x, hh, wh;
    if (s < 34)      { hh = 0;  wh = s; }
    else if (s < 68) { hh = 33; wh = s - 34; }
    else             { int k = s - 68; hh = 1 + (k >> 1); wh = (k & 1) * 33; }
    uint4 z; z.x = z.y = z.z = z.w = 0u;
    uint4* p = (uint4*)(xp + ((size_t)hh * XW + wh) * XP_CB) + t;
#pragma unroll
    for (int q = 0; q < 4; ++q) p[q * 256] = z;
  }
}

// ---- pass 2: per-pooled-cell GEMMs + bias + relu + maxpool ----
// K-order is r-major (kk' = r*64 + c): chunk kc -> fixed 3x3 tap r = kc>>1,
// channels c0..c0+31 with c0 = (kc&1)*32. A-gather is then affine (one base,
// 8 offset-folded loads); weight rows are read permuted (stride-9 row order)
// but each load stays a contiguous 256B segment along CO.
__global__ __launch_bounds__(512, 4) void local_gemm_pool(
    const float* __restrict__ Wt, const float* __restrict__ bias,
    const unsigned short* __restrict__ xp, float* __restrict__ out) {
  __shared__ __align__(16) unsigned short Asl[2][BB][LDK];   // 20.0 KB
  __shared__ __align__(16) unsigned short Bsl[2][COB][LDK];  // 10.0 KB

  const int tid  = threadIdx.x;
  const int lane = tid & 63;
  const int wave = tid >> 6;   // 0..7

  // XCD swizzle: blockIdx%8 = XCD; all pw and both coh of a ph-row on one XCD
  // so output 64B lines merge in that XCD's L2 and the coh pair shares xp.
  const int bidx = blockIdx.x;
  const int x8 = bidx & 7, j = bidx >> 3;       // j 0..63
  const int coh = j & 1;
  const int pw  = (j >> 1) & 15;
  const int ph  = 2 * x8 + (j >> 5);
  const int co0 = coh * COB;

  // staging ids
  const int sa = tid & 127;      // A: batch lane (256B coalesced)
  const int ka = tid >> 7;       // 0..3 : 8-channel group
  const int sb = tid & 63;       // B: c_out lane (256B coalesced)
  const int kb = tid >> 6;       // 0..7 : 4-channel group (wave uniform)

  // compute ids (mfma 16x16x32 layouts, HW-verified)
  const int r16 = lane & 15;
  const int q8  = (lane >> 4) * 8;
  const int m0  = (wave >> 2) * 64;   // batch tile: 2 x 64
  const int n0  = (wave & 3) * 16;    // c_out tile: 4 x 16

  f32x4 acc[4] = {};
  f32x4 rmx[4] = {};   // relu => max >= 0, so 0-init is exact

  float          breg0[4], breg1[4];
  unsigned short areg0[8], areg1[8];

  auto issue = [&](int it, float* br, unsigned short* ar) {
    const int loc = it / 18, kc = it % 18;
    const int r = kc >> 1, c0 = (kc & 1) * 32;   // tap, channel-half
    const int di = r / 3, dj = r % 3;
    const int oh = 2 * ph + (loc >> 1), ow = 2 * pw + (loc & 1);
    const int l  = oh * OW + ow;
    // weight rows f = (c0 + kb*4 + i)*9 + r, contiguous 256B along CO
    const float* wp = Wt + ((size_t)l * IF + (size_t)(c0 + kb * 4) * 9 + r) * CO
                         + co0 + sb;
#pragma unroll
    for (int i = 0; i < 4; ++i) br[i] = wp[(size_t)i * 9 * CO];
    // A: haloed pixel (oh+di, ow+dj), channels c0+ka*8 .. +8, batch lane sa
    const unsigned short* ap = xp + ((size_t)(oh + di) * XW + (ow + dj)) * XP_CB
                                  + (c0 + ka * 8) * BB + sa;
#pragma unroll
    for (int i = 0; i < 8; ++i) ar[i] = ap[i * BB];   // 256B stride, offset-folded
  };

  auto writeLds = [&](int it, const float* br, const unsigned short* ar) {
    const int bufI = it & 1;
    uint2 vb;
    vb.x = cvt_pk_bf16(br[0], br[1]);
    vb.y = cvt_pk_bf16(br[2], br[3]);
    *(uint2*)&Bsl[bufI][sb][kb * 4] = vb;    // b64, 8B-aligned
    short8 va;
#pragma unroll
    for (int i = 0; i < 8; ++i) va[i] = (short)ar[i];
    *(short8*)&Asl[bufI][sa][ka * 8] = va;   // b128, 16B-aligned
  };

  auto computeChunk = [&](int it) {
    const int bufI = it & 1;
    short8 af[4], bf;
#pragma unroll
    for (int tm = 0; tm < 4; ++tm)
      af[tm] = *(const short8*)&Asl[bufI][m0 + tm * 16 + r16][q8];
    bf = *(const short8*)&Bsl[bufI][n0 + r16][q8];
#pragma unroll
    for (int tm = 0; tm < 4; ++tm)
      acc[tm] = __builtin_amdgcn_mfma_f32_16x16x32_bf16(af[tm], bf, acc[tm], 0, 0, 0);
  };

  auto finishLoc = [&](int loc) {
    const int oh = 2 * ph + (loc >> 1), ow = 2 * pw + (loc & 1);
    const int l  = oh * OW + ow;
    const float bv = bias[l * CO + co0 + n0 + r16];
#pragma unroll
    for (int tm = 0; tm < 4; ++tm)
#pragma unroll
      for (int e = 0; e < 4; ++e) {
        float v = acc[tm][e] + bv;
        v = v > 0.f ? v : 0.f;
        rmx[tm][e] = fmaxf(rmx[tm][e], v);
        acc[tm][e] = 0.f;
      }
  };

  // 2-buffer reg-staged pipeline prologue
  issue(0, breg0, areg0);
  issue(1, breg1, areg1);
  writeLds(0, breg0, areg0);   // one prologue vmcnt stall
  __syncthreads();             // buf0 ready

  for (int it2 = 0; it2 < NIT; it2 += 2) {
    // even slot: compute buf0, stage buf1
    if (it2 + 2 < NIT) issue(it2 + 2, breg0, areg0);
    computeChunk(it2);
    writeLds(it2 + 1, breg1, areg1);          // it2+1 <= NIT-1 always
    __syncthreads();
    // odd slot: compute buf1, stage buf0
    const int ito = it2 + 1;
    if (ito + 2 < NIT) issue(ito + 2, breg1, areg1);
    computeChunk(ito);
    if (ito + 1 < NIT) writeLds(ito + 1, breg0, areg0);
    if (ito % 18 == 17) finishLoc(ito / 18);  // loc boundaries are odd its
    __syncthreads();
  }

  // store pooled tile; C/D: col=lane&15, row=(lane>>4)*4+e
  float* op = out + (ph * 16 + pw);
  const int col = co0 + n0 + r16;             // c_out
#pragma unroll
  for (int tm = 0; tm < 4; ++tm)
#pragma unroll
    for (int e = 0; e < 4; ++e) {
      const int row = m0 + tm * 16 + (lane >> 4) * 4 + e;  // batch
      op[((size_t)row * CO + col) * 256] = rmx[tm][e];
    }
}

extern "C" void kernel_launch(void* const* d_in, const int* in_sizes, int n_in,
                              void* d_out, int out_size, void* d_ws, size_t ws_size,
                              hipStream_t stream) {
  (void)in_sizes; (void)n_in; (void)out_size; (void)ws_size;
  const float* x  = (const float*)d_in[0];
  const float* w  = (const float*)d_in[1];
  const float* bs = (const float*)d_in[2];
  float* out = (float*)d_out;
  unsigned short* xp = (unsigned short*)d_ws;   // needs 18.94 MB scratch

  transpose_x<<<dim3(CI * HH), dim3(256), 0, stream>>>(x, xp);
  local_gemm_pool<<<dim3(512), dim3(512), 0, stream>>>(w, bs, xp, out);
}

// Round 3
// 451.973 us; speedup vs baseline: 1.0597x; 1.0184x over previous
//
#include <hip/hip_runtime.h>

// Problem constants
#define BB   128   // batch
#define CI   64    // in channels
#define HH   32
#define WW   32
#define CO   128   // out channels
#define IF   576   // CI*9
#define OW   32    // conv out w
#define XH   34    // haloed H
#define XW   34    // haloed W
// x' layout: [XH][XW][CI][BB] bf16(ushort);  (h',w',c,b) with h'=h+1 halo
#define XP_CB    (CI*BB)              // 8192
#define XP_ELEMS ((size_t)XH*XW*CI*BB)  // 9,469,952
#define BKC  64    // K-chunk = one full 3x3 tap (64 channels)
#define NCH  36    // 4 locations * 9 taps
#define LDK  72    // padded LDS row: 144B = 9*16B (odd 16B multiple -> b128-clean)
#define COB  64    // per-block c_out tile (CO split across 2 blocks)

using short8 = __attribute__((ext_vector_type(8))) short;
using f32x4  = __attribute__((ext_vector_type(4))) float;

__device__ __forceinline__ unsigned short f2bf(float f) {
  union { float f; unsigned int u; } v; v.f = f;
  unsigned int u = v.u;
  u = (u + 0x7FFFu + ((u >> 16) & 1u)) >> 16;   // RNE; inputs are finite
  return (unsigned short)u;
}

// HW packed fp32->bf16 (RNE), no builtin on gfx950 -> inline asm
__device__ __forceinline__ unsigned int cvt_pk_bf16(float lo, float hi) {
  unsigned int r;
  asm("v_cvt_pk_bf16_f32 %0, %1, %2" : "=v"(r) : "v"(lo), "v"(hi));
  return r;
}

// ---- pass 1: x (B,C,H,W) fp32 -> x' (H+2,W+2,C,B) bf16; halo zeroed by
// the first 132 blocks (replaces the 19 MB memset with 2.2 MB of writes) ----
__global__ __launch_bounds__(256) void transpose_x(
    const float* __restrict__ x, unsigned short* __restrict__ xp) {
  const int c = blockIdx.x >> 5;   // 0..63
  const int h = blockIdx.x & 31;   // 0..31
  __shared__ __align__(16) unsigned short tile[32][136]; // 272B row: 16B-mult
  const int t = threadIdx.x;
  const int w = t & 31, b0 = t >> 5;         // b0 0..7
#pragma unroll
  for (int p = 0; p < 16; ++p) {
    int b = b0 + p * 8;
    float v = x[(((size_t)b * CI + c) * HH + h) * WW + w];
    tile[w][b] = f2bf(v);
  }
  __syncthreads();
  const int w2 = t >> 3;                 // 0..31
  const int bb = (t & 7) * 16;           // 0..112
  const unsigned short* src = &tile[w2][bb];
  unsigned short* dst = xp + ((size_t)(h + 1) * XW + (w2 + 1)) * XP_CB + c * BB + bb;
  *(uint4*)(dst)     = *(const uint4*)(src);
  *(uint4*)(dst + 8) = *(const uint4*)(src + 8);

  // halo zero: 132 spans of 8192 ushorts (16 KB each)
  if (blockIdx.x < 132) {
    int s = blockIdx.x, hh, wh;
    if (s < 34)      { hh = 0;  wh = s; }
    else if (s < 68) { hh = 33; wh = s - 34; }
    else             { int k = s - 68; hh = 1 + (k >> 1); wh = (k & 1) * 33; }
    uint4 z; z.x = z.y = z.z = z.w = 0u;
    uint4* p = (uint4*)(xp + ((size_t)hh * XW + wh) * XP_CB) + t;
#pragma unroll
    for (int q = 0; q < 4; ++q) p[q * 256] = z;
  }
}

// ---- pass 2: per-pooled-cell GEMMs + bias + relu + maxpool ----
// K-chunk = one full 3x3 tap (BKC=64): A-gather per chunk is one contiguous
// 16 KB block of xp; weight rows f = c*9 + tap (stride-9 row order, each a
// contiguous 256B segment along CO). 36 chunk-slots (vs 72 at BK=32): half
// the barriers, double the per-slot HBM budget -> the 1-slot reg-prefetch
// lookahead covers ~3200 cy, well past loaded HBM latency.
__global__ __launch_bounds__(512, 4) void local_gemm_pool(
    const float* __restrict__ Wt, const float* __restrict__ bias,
    const unsigned short* __restrict__ xp, float* __restrict__ out) {
  __shared__ __align__(16) unsigned short Asl[2][BB][LDK];   // 36.9 KB
  __shared__ __align__(16) unsigned short Bsl[2][COB][LDK];  // 18.4 KB

  const int tid  = threadIdx.x;
  const int lane = tid & 63;
  const int wave = tid >> 6;   // 0..7

  // XCD swizzle: blockIdx%8 = XCD; all pw and both coh of a ph-row on one XCD
  // so output 64B lines merge in that XCD's L2 and the coh pair shares xp
  // (per-XCD xp footprint ~3.3 MB < 4 MB L2).
  const int bidx = blockIdx.x;
  const int x8 = bidx & 7, j = bidx >> 3;       // j 0..63
  const int coh = j & 1;
  const int pw  = (j >> 1) & 15;
  const int ph  = 2 * x8 + (j >> 5);
  const int co0 = coh * COB;

  // staging ids
  const int sa = tid & 127;      // A: batch lane (256B coalesced)
  const int ka = tid >> 7;       // 0..3 : 16-channel group
  const int sb = tid & 63;       // B: c_out lane (256B coalesced)
  const int kb = tid >> 6;       // 0..7 : 8-channel group (wave uniform)

  // compute ids (mfma 16x16x32 layouts, HW-verified)
  const int r16 = lane & 15;
  const int q8  = (lane >> 4) * 8;
  const int m0  = (wave >> 2) * 64;   // batch tile: 2 x 64
  const int n0  = (wave & 3) * 16;    // c_out tile: 4 x 16

  f32x4 acc[4] = {};
  f32x4 rmx[4] = {};   // relu => max >= 0, so 0-init is exact

  float          breg0[8], breg1[8];
  unsigned short areg0[16], areg1[16];

  auto issue = [&](int it, float* br, unsigned short* ar) {
    const int loc = it / 9, kc = it % 9;          // kc = 3x3 tap index
    const int di = kc / 3, dj = kc % 3;
    const int oh = 2 * ph + (loc >> 1), ow = 2 * pw + (loc & 1);
    const int l  = oh * OW + ow;
    // weight rows f = (kb*8 + i)*9 + kc, contiguous 256B along CO
    const float* wp = Wt + ((size_t)l * IF + (size_t)(kb * 8) * 9 + kc) * CO
                         + co0 + sb;
#pragma unroll
    for (int i = 0; i < 8; ++i) br[i] = wp[(size_t)i * 9 * CO];
    // A: haloed pixel (oh+di, ow+dj), channels ka*16..+16, batch lane sa
    const unsigned short* ap = xp + ((size_t)(oh + di) * XW + (ow + dj)) * XP_CB
                                  + (ka * 16) * BB + sa;
#pragma unroll
    for (int i = 0; i < 16; ++i) ar[i] = ap[i * BB];  // 256B stride, offset-folded
  };

  auto writeLds = [&](int it, const float* br, const unsigned short* ar) {
    const int bufI = it & 1;
    uint4 vb;
    vb.x = cvt_pk_bf16(br[0], br[1]);
    vb.y = cvt_pk_bf16(br[2], br[3]);
    vb.z = cvt_pk_bf16(br[4], br[5]);
    vb.w = cvt_pk_bf16(br[6], br[7]);
    *(uint4*)&Bsl[bufI][sb][kb * 8] = vb;    // b128, 16B-aligned
#pragma unroll
    for (int p = 0; p < 2; ++p) {
      short8 va;
#pragma unroll
      for (int i = 0; i < 8; ++i) va[i] = (short)ar[p * 8 + i];
      *(short8*)&Asl[bufI][sa][ka * 16 + p * 8] = va;   // b128, 16B-aligned
    }
  };

  auto computeChunk = [&](int it) {
    const int bufI = it & 1;
#pragma unroll
    for (int h = 0; h < 2; ++h) {            // two K=32 halves of the 64-chunk
      const int col = h * 32 + q8;
      short8 af[4], bf;
#pragma unroll
      for (int tm = 0; tm < 4; ++tm)
        af[tm] = *(const short8*)&Asl[bufI][m0 + tm * 16 + r16][col];
      bf = *(const short8*)&Bsl[bufI][n0 + r16][col];
#pragma unroll
      for (int tm = 0; tm < 4; ++tm)
        acc[tm] = __builtin_amdgcn_mfma_f32_16x16x32_bf16(af[tm], bf, acc[tm], 0, 0, 0);
    }
  };

  auto finishLoc = [&](int loc) {
    const int oh = 2 * ph + (loc >> 1), ow = 2 * pw + (loc & 1);
    const int l  = oh * OW + ow;
    const float bv = bias[l * CO + co0 + n0 + r16];
#pragma unroll
    for (int tm = 0; tm < 4; ++tm)
#pragma unroll
      for (int e = 0; e < 4; ++e) {
        float v = acc[tm][e] + bv;
        v = v > 0.f ? v : 0.f;
        rmx[tm][e] = fmaxf(rmx[tm][e], v);
        acc[tm][e] = 0.f;
      }
  };

  // 2-buffer reg-staged pipeline prologue
  issue(0, breg0, areg0);
  issue(1, breg1, areg1);
  writeLds(0, breg0, areg0);   // one prologue vmcnt stall
  __syncthreads();             // buf0 ready

  for (int it2 = 0; it2 < NCH; it2 += 2) {
    // even slot: compute buf0, stage buf1
    if (it2 + 2 < NCH) issue(it2 + 2, breg0, areg0);
    computeChunk(it2);
    writeLds(it2 + 1, breg1, areg1);          // it2+1 <= NCH-1 always
    if (it2 % 9 == 8) finishLoc(it2 / 9);     // locs 0,2 end on even its (8,26)
    __syncthreads();
    // odd slot: compute buf1, stage buf0
    const int ito = it2 + 1;
    if (ito + 2 < NCH) issue(ito + 2, breg1, areg1);
    computeChunk(ito);
    if (ito + 1 < NCH) writeLds(ito + 1, breg0, areg0);
    if (ito % 9 == 8) finishLoc(ito / 9);     // locs 1,3 end on odd its (17,35)
    __syncthreads();
  }

  // store pooled tile; C/D: col=lane&15, row=(lane>>4)*4+e
  float* op = out + (ph * 16 + pw);
  const int col = co0 + n0 + r16;             // c_out
#pragma unroll
  for (int tm = 0; tm < 4; ++tm)
#pragma unroll
    for (int e = 0; e < 4; ++e) {
      const int row = m0 + tm * 16 + (lane >> 4) * 4 + e;  // batch
      op[((size_t)row * CO + col) * 256] = rmx[tm][e];
    }
}

extern "C" void kernel_launch(void* const* d_in, const int* in_sizes, int n_in,
                              void* d_out, int out_size, void* d_ws, size_t ws_size,
                              hipStream_t stream) {
  (void)in_sizes; (void)n_in; (void)out_size; (void)ws_size;
  const float* x  = (const float*)d_in[0];
  const float* w  = (const float*)d_in[1];
  const float* bs = (const float*)d_in[2];
  float* out = (float*)d_out;
  unsigned short* xp = (unsigned short*)d_ws;   // needs 18.94 MB scratch

  transpose_x<<<dim3(CI * HH), dim3(256), 0, stream>>>(x, xp);
  local_gemm_pool<<<dim3(512), dim3(512), 0, stream>>>(w, bs, xp, out);
}